// Round 8
// baseline (21800.757 us; speedup 1.0000x reference)
//
#include <hip/hip_runtime.h>
#include <hip/hip_bf16.h>
#include <cstdint>
#include <cstddef>

// Problem: S=4096, I=1024, H=1024. 4H=4096. ALL tensors fp32 (per reference).
// out (fp32): all_hidden (4096 x 2048) then final_h (2048), flat.

typedef __attribute__((ext_vector_type(8))) short short8;
typedef __attribute__((ext_vector_type(4))) short short4v;
typedef __attribute__((ext_vector_type(4))) float float4v;
typedef unsigned long long ull;

__device__ __forceinline__ float bf2f(unsigned short u) {
    return __uint_as_float(((unsigned int)u) << 16);
}
__device__ __forceinline__ unsigned short f2bf(float f) {
    __hip_bfloat16 h = __float2bfloat16(f);  // RNE
    return *reinterpret_cast<unsigned short*>(&h);
}
__device__ __forceinline__ float sigm(float x) {
    return 1.f / (1.f + __expf(-x));
}
__device__ __forceinline__ float tanh_fast(float x) {
    return 1.f - 2.f / (__expf(2.f * x) + 1.f);   // exact at +-inf, ~1e-6 rel
}

// ---------------------------------------------------------------------------
// Kernel A: x_proj[d][t][j] = b[d][j] + sum_k inp[t][k] * W[d][j][1024+k]
// fp32 -> bf16 LDS tiles -> mfma_f32_16x16x32_bf16 -> fp32 x_proj.
// ---------------------------------------------------------------------------
__global__ __launch_bounds__(256)
void xproj_gemm(const float* __restrict__ inp,
                const float* __restrict__ fw,
                const float* __restrict__ fb,
                const float* __restrict__ bw,
                const float* __restrict__ bb,
                float* __restrict__ xp)
{
    const int d  = blockIdx.z;
    const float* W = d ? bw : fw;
    const float* B = d ? bb : fb;
    const int t0 = blockIdx.y * 128;
    const int n0 = blockIdx.x * 128;

    __shared__ __align__(16) short Ash[128 * 32];
    __shared__ __align__(16) short Bsh[128 * 32];

    const int tid  = threadIdx.x;
    const int lane = tid & 63;
    const int wave = tid >> 6;
    const int wm = (wave & 1) * 64;
    const int wn = (wave >> 1) * 64;
    const int quad = lane >> 4;
    const int l15  = lane & 15;

    float4v acc[4][4];
    float4v zero4 = {0.f, 0.f, 0.f, 0.f};
#pragma unroll
    for (int mi = 0; mi < 4; mi++)
#pragma unroll
        for (int ni = 0; ni < 4; ni++) acc[mi][ni] = zero4;

    for (int k0 = 0; k0 < 1024; k0 += 32) {
#pragma unroll
        for (int s = 0; s < 4; s++) {
            int c   = tid + s * 256;       // 0..1023
            int row = c >> 3;              // 0..127
            int ko  = (c & 7) * 4;         // 0..28
            float4v va = *(const float4v*)&inp[(size_t)(t0 + row) * 1024 + k0 + ko];
            float4v vb = *(const float4v*)&W[(size_t)(n0 + row) * 2048 + 1024 + k0 + ko];
            short4v sa, sb;
#pragma unroll
            for (int e = 0; e < 4; e++) {
                sa[e] = (short)f2bf(va[e]);
                sb[e] = (short)f2bf(vb[e]);
            }
            *(short4v*)&Ash[row * 32 + ko] = sa;
            *(short4v*)&Bsh[row * 32 + ko] = sb;
        }
        __syncthreads();

        short8 af[4], bfr[4];
#pragma unroll
        for (int mi = 0; mi < 4; mi++)
            af[mi] = *(const short8*)&Ash[(wm + mi * 16 + l15) * 32 + quad * 8];
#pragma unroll
        for (int ni = 0; ni < 4; ni++)
            bfr[ni] = *(const short8*)&Bsh[(wn + ni * 16 + l15) * 32 + quad * 8];

#pragma unroll
        for (int mi = 0; mi < 4; mi++)
#pragma unroll
            for (int ni = 0; ni < 4; ni++)
                acc[mi][ni] = __builtin_amdgcn_mfma_f32_16x16x32_bf16(
                    af[mi], bfr[ni], acc[mi][ni], 0, 0, 0);
        __syncthreads();
    }

#pragma unroll
    for (int ni = 0; ni < 4; ni++) {
        int gc = n0 + wn + ni * 16 + l15;
        float bias = B[gc];
#pragma unroll
        for (int mi = 0; mi < 4; mi++) {
#pragma unroll
            for (int r = 0; r < 4; r++) {
                int gr = t0 + wm + mi * 16 + quad * 4 + r;
                xp[((size_t)d * 4096 + gr) * 4096 + gc] = acc[mi][ni][r] + bias;
            }
        }
    }
}

// ---------------------------------------------------------------------------
// Kernel B: persistent bidirectional LSTM recurrence, fence-free tagged sync.
//
// Sync scheme: hq is uint32[dir][2][1024]; each word = fp32 h with its 2 LOW
// MANTISSA BITS replaced by (step & 3). Parity double-buffer: a polled slot
// only ever holds step t or t-2 -> 2-bit tag disambiguates; perturbation
// <=3 ulp. memset-0 init == tag 0 == h^0. All hq traffic is RELAXED
// agent-scope atomics (no cache-maintenance storms).
//
// Round-8 structure: WAVE-AUTONOMOUS, ZERO barriers per step.
//  - wave wv of a block owns units {u0+2wv, u0+2wv+1} end-to-end (r5 lane
//    layout: cc=l>>3 col-chunk, g=(l&7)>>1 gate, p=l&1 unit parity; 128-col
//    partial per lane; shfl_xor tree 8/16/32 reduces; gates in-wave; lane 0
//    publishes the 8B pair).
//  - each wave polls the ENTIRE 1024-unit vector itself: 64 lanes x 8
//    pair-words, load k covers words 64k+l (coalesced 512B). Merged check,
//    reload only misses, s_sleep(1) backoff (r3-proven). Staged into a
//    WAVE-PRIVATE padded LDS buffer; write->read ordered by lgkmcnt(0)
//    only (same wave) -> no __syncthreads anywhere in the loop.
//  - deletes S2, psum, and the serial wave-0 epilogue (~700-900 cy of
//    post-FMA coupling in r4). r5's failure was its PRE-FMA block barrier;
//    this keeps r5's epilogue without any barrier.
//
// Safety: a wave publishes t+1 only after detecting ALL of step t; any
// tag-t word proves its producer consumed all of t-1 (program order), so
// overwriting t-1 slots (same parity as t+1) is safe. Tags mod 4 separate
// t+1 from t-1.
// ---------------------------------------------------------------------------
template <int FUSED>
__global__ __launch_bounds__(512, 2)
void lstm_rec(const float* __restrict__ fw,
              const float* __restrict__ bw,
              const float* __restrict__ fb,
              const float* __restrict__ bb,
              const float* __restrict__ inp,
              const float* __restrict__ xp,
              unsigned int* __restrict__ hq,     // [dir][2][1024] tagged f32
              float* __restrict__ out)
{
    const int dir  = blockIdx.x & 1;
    const int slot = blockIdx.x >> 1;          // 0..63
    const int u0   = slot * 16;                // 16 units per block
    const int T    = threadIdx.x;              // 0..511
    const int wv   = T >> 6;                   // wave 0..7 -> units u0+2wv,+1
    const int l    = T & 63;
    const int cc   = l >> 3;                   // col chunk 0..7
    const int p    = l & 1;                    // unit parity
    const int g    = (l & 7) >> 1;             // gate 0..3 (f,i,g,o)
    const int ug   = u0 + 2 * wv;              // wave's even unit
    const int j    = g * 1024 + ug + p;        // this lane's global z-row
    const float* W = dir ? bw : fw;

    // wave-private, chunk-padded h staging (132 floats per 128-col chunk:
    // chunk bases differ by 4 banks -> the 8 distinct ds_read_b128 addrs
    // per instruction are conflict-free)
    __shared__ __align__(16) float hsh[8][8 * 132];
    __shared__ __align__(16) float xsh[8][8 * 132];   // FUSED only

    // Wh weights (cols [cc*128,+128) of row j) -> regs
    float w[128];
    {
        const float* wr = W + (size_t)j * 2048 + cc * 128;
#pragma unroll
        for (int i = 0; i < 32; i++)
            *(float4v*)&w[4 * i] = *(const float4v*)&wr[4 * i];
    }

    // FUSED: Wx packed bf16 + per-row bias (cc==0 lanes carry the bias)
    unsigned int w2[64];
    float brow = 0.f;
    if (FUSED) {
        const float* wr2 = W + (size_t)j * 2048 + 1024 + cc * 128;
#pragma unroll
        for (int i = 0; i < 32; i++) {
            float4v v = *(const float4v*)&wr2[4 * i];
            w2[2 * i]     = (unsigned int)f2bf(v[0]) | ((unsigned int)f2bf(v[1]) << 16);
            w2[2 * i + 1] = (unsigned int)f2bf(v[2]) | ((unsigned int)f2bf(v[3]) << 16);
        }
        if (cc == 0)
            brow = (dir ? bb : fb)[j];
    }

    unsigned int* hqd = hq + dir * 2048;
    float* hw = hsh[wv];
    float* xw = xsh[wv];
    float c = 0.f;   // cell state for unit ug+p (replicated across p-lanes)

    for (int t = 0; t < 4096; t++) {
        const int tr  = dir ? (4095 - t) : t;
        const int par = t & 1;

        // independent global loads first (long latency, off critical path)
        float xv = 0.f;
        if (FUSED) {
#pragma unroll
            for (int kk = 0; kk < 4; kk++) {
                float4v iv = ((const float4v*)&inp[(size_t)tr * 1024])[64 * kk + l];
                int base = kk * 256 + 4 * l;                  // global float idx
                *(float4v*)&xw[(base >> 7) * 132 + (base & 127)] = iv;
            }
        } else if (cc == 0) {
            xv = xp[((size_t)dir * 4096 + tr) * 4096 + j];
        }

        // wave-autonomous poll of the FULL vector: lane l owns pair-words
        // {64k+l : k=0..7} (load k is 512B contiguous across the wave)
        {
            const ull tagm = 0x0000000300000003ull;
            const ull tag2 = ((ull)((unsigned)t & 3u)) * 0x100000001ull;
            ull* qb = (ull*)(hqd + par * 1024);
            ull got[8];
#pragma unroll
            for (int k = 0; k < 8; k++)
                got[k] = __hip_atomic_load(qb + 64 * k + l,
                                           __ATOMIC_RELAXED, __HIP_MEMORY_SCOPE_AGENT);
            for (;;) {
                unsigned nm = 0;
#pragma unroll
                for (int k = 0; k < 8; k++)
                    if ((got[k] & tagm) != tag2) nm |= (1u << k);
                if (!nm) break;
                __builtin_amdgcn_s_sleep(1);   // ~64 cy backoff, decongest fabric
#pragma unroll
                for (int k = 0; k < 8; k++)
                    if (nm & (1u << k))
                        got[k] = __hip_atomic_load(qb + 64 * k + l,
                                                   __ATOMIC_RELAXED, __HIP_MEMORY_SCOPE_AGENT);
            }
            // stage: word 64k+l = units 128k+2l -> chunk k, offset 2l
#pragma unroll
            for (int k = 0; k < 8; k++)
                *(ull*)&hw[k * 132 + 2 * l] = got[k];
        }
        // same-wave LDS write->read ordering; NO block barrier anywhere
        asm volatile("s_waitcnt lgkmcnt(0)" ::: "memory");

        // z partial: 128 reg-resident fp32 MACs over this lane's col window
        float a0 = 0.f, a1 = 0.f, a2 = 0.f, a3 = 0.f;
        const float4v* h4 = (const float4v*)&hw[cc * 132];
#pragma unroll
        for (int i = 0; i < 32; i++) {
            float4v hv = h4[i];
            a0 = __builtin_fmaf(w[4 * i + 0], hv.x, a0);
            a1 = __builtin_fmaf(w[4 * i + 1], hv.y, a1);
            a2 = __builtin_fmaf(w[4 * i + 2], hv.z, a2);
            a3 = __builtin_fmaf(w[4 * i + 3], hv.w, a3);
        }
        if (FUSED) {
            const float* xs = &xw[cc * 132];
#pragma unroll
            for (int i = 0; i < 64; i++) {
                unsigned int dv = w2[i];
                a0 = __builtin_fmaf(bf2f((unsigned short)(dv & 0xffffu)),
                                    xs[2 * i], a0);
                a1 = __builtin_fmaf(bf2f((unsigned short)(dv >> 16)),
                                    xs[2 * i + 1], a1);
            }
        }
        float s = ((a0 + a1) + (a2 + a3)) + xv;   // xv = xp (cc==0) or 0
        if (FUSED && cc == 0) s += brow;

        // reduce over the 8 col-chunks: lanes {l, l^8, l^16, l^32} share row
        s += __shfl_xor(s, 8);
        s += __shfl_xor(s, 16);
        s += __shfl_xor(s, 32);
        // every lane now holds full z for its row (l&7)

        // gates for unit parity p (rows p, 2+p, 4+p, 6+p = f,i,g,o)
        float z0 = __shfl(s, p);
        float z1 = __shfl(s, 2 + p);
        float z2 = __shfl(s, 4 + p);
        float z3 = __shfl(s, 6 + p);
        c = sigm(z0) * c + sigm(z1) * tanh_fast(z2);
        float hv = sigm(z3) * tanh_fast(c);

        // lane 0 publishes the wave's 8B tagged pair FIRST, then out stores
        unsigned int hb = (__float_as_uint(hv) & ~3u) | ((unsigned)(t + 1) & 3u);
        unsigned int hb1 = __shfl(hb, 1);
        float hv1 = __shfl(hv, 1);
        if (l == 0) {
            ull pw = ((ull)hb1 << 32) | (ull)hb;
            __hip_atomic_store((ull*)&hqd[((t + 1) & 1) * 1024 + ug], pw,
                               __ATOMIC_RELAXED, __HIP_MEMORY_SCOPE_AGENT);
            float2 o2 = {hv, hv1};
            *(float2*)&out[(size_t)tr * 2048 + dir * 1024 + ug] = o2;
            if (t == 4095)   // final_h: fwd = hs[4095], bwd = hs[0]
                *(float2*)&out[(size_t)4096 * 2048 + dir * 1024 + ug] = o2;
        }
    }
}

// ---------------------------------------------------------------------------
extern "C" void kernel_launch(void* const* d_in, const int* in_sizes, int n_in,
                              void* d_out, int out_size, void* d_ws, size_t ws_size,
                              hipStream_t stream)
{
    const float* inp = (const float*)d_in[0];
    const float* fw  = (const float*)d_in[1];
    const float* fb  = (const float*)d_in[2];
    const float* bw  = (const float*)d_in[3];
    const float* bb  = (const float*)d_in[4];

    char* ws = (char*)d_ws;
    unsigned int* hq = (unsigned int*)ws;          // 16 KB: [dir][2][1024] x 4B
    float* xp = (float*)(ws + 32768);              // x_proj: 2 x 4096 x 4096 fp32

    const size_t XP_BYTES = 2ull * 4096 * 4096 * 4;   // 134.2 MB
    const int have_xp = (ws_size >= 32768 + XP_BYTES);

    hipMemsetAsync(ws, 0, 16384, stream);   // tag 0 / h=0 == step-0 state

    float* outp = (float*)d_out;
    if (have_xp) {
        dim3 gg(32, 32, 2);
        xproj_gemm<<<gg, 256, 0, stream>>>(inp, fw, fb, bw, bb, xp);
        lstm_rec<0><<<dim3(128), 512, 0, stream>>>(fw, bw, fb, bb, inp, xp,
                                                   hq, outp);
    } else {
        lstm_rec<1><<<dim3(128), 512, 0, stream>>>(fw, bw, fb, bb, inp, nullptr,
                                                   hq, outp);
    }
}

// Round 9
// 7613.287 us; speedup vs baseline: 2.8635x; 2.8635x over previous
//
#include <hip/hip_runtime.h>
#include <hip/hip_bf16.h>
#include <cstdint>
#include <cstddef>

// Problem: S=4096, I=1024, H=1024. 4H=4096. ALL tensors fp32 (per reference).
// out (fp32): all_hidden (4096 x 2048) then final_h (2048), flat.

typedef __attribute__((ext_vector_type(8))) short short8;
typedef __attribute__((ext_vector_type(4))) short short4v;
typedef __attribute__((ext_vector_type(4))) float float4v;
typedef __attribute__((ext_vector_type(2))) float float2v;
typedef unsigned long long ull;

__device__ __forceinline__ float bf2f(unsigned short u) {
    return __uint_as_float(((unsigned int)u) << 16);
}
__device__ __forceinline__ unsigned short f2bf(float f) {
    __hip_bfloat16 h = __float2bfloat16(f);  // RNE
    return *reinterpret_cast<unsigned short*>(&h);
}
__device__ __forceinline__ float sigm(float x) {
    return 1.f / (1.f + __expf(-x));
}
__device__ __forceinline__ float tanh_fast(float x) {
    return 1.f - 2.f / (__expf(2.f * x) + 1.f);   // exact at +-inf, ~1e-6 rel
}

// ---------------------------------------------------------------------------
// Kernel A: x_proj[d][t][j] = b[d][j] + sum_k inp[t][k] * W[d][j][1024+k]
// fp32 -> bf16 LDS tiles -> mfma_f32_16x16x32_bf16 -> fp32 x_proj.
// ---------------------------------------------------------------------------
__global__ __launch_bounds__(256)
void xproj_gemm(const float* __restrict__ inp,
                const float* __restrict__ fw,
                const float* __restrict__ fb,
                const float* __restrict__ bw,
                const float* __restrict__ bb,
                float* __restrict__ xp)
{
    const int d  = blockIdx.z;
    const float* W = d ? bw : fw;
    const float* B = d ? bb : fb;
    const int t0 = blockIdx.y * 128;
    const int n0 = blockIdx.x * 128;

    __shared__ __align__(16) short Ash[128 * 32];
    __shared__ __align__(16) short Bsh[128 * 32];

    const int tid  = threadIdx.x;
    const int lane = tid & 63;
    const int wave = tid >> 6;
    const int wm = (wave & 1) * 64;
    const int wn = (wave >> 1) * 64;
    const int quad = lane >> 4;
    const int l15  = lane & 15;

    float4v acc[4][4];
    float4v zero4 = {0.f, 0.f, 0.f, 0.f};
#pragma unroll
    for (int mi = 0; mi < 4; mi++)
#pragma unroll
        for (int ni = 0; ni < 4; ni++) acc[mi][ni] = zero4;

    for (int k0 = 0; k0 < 1024; k0 += 32) {
#pragma unroll
        for (int s = 0; s < 4; s++) {
            int c   = tid + s * 256;       // 0..1023
            int row = c >> 3;              // 0..127
            int ko  = (c & 7) * 4;         // 0..28
            float4v va = *(const float4v*)&inp[(size_t)(t0 + row) * 1024 + k0 + ko];
            float4v vb = *(const float4v*)&W[(size_t)(n0 + row) * 2048 + 1024 + k0 + ko];
            short4v sa, sb;
#pragma unroll
            for (int e = 0; e < 4; e++) {
                sa[e] = (short)f2bf(va[e]);
                sb[e] = (short)f2bf(vb[e]);
            }
            *(short4v*)&Ash[row * 32 + ko] = sa;
            *(short4v*)&Bsh[row * 32 + ko] = sb;
        }
        __syncthreads();

        short8 af[4], bfr[4];
#pragma unroll
        for (int mi = 0; mi < 4; mi++)
            af[mi] = *(const short8*)&Ash[(wm + mi * 16 + l15) * 32 + quad * 8];
#pragma unroll
        for (int ni = 0; ni < 4; ni++)
            bfr[ni] = *(const short8*)&Bsh[(wn + ni * 16 + l15) * 32 + quad * 8];

#pragma unroll
        for (int mi = 0; mi < 4; mi++)
#pragma unroll
            for (int ni = 0; ni < 4; ni++)
                acc[mi][ni] = __builtin_amdgcn_mfma_f32_16x16x32_bf16(
                    af[mi], bfr[ni], acc[mi][ni], 0, 0, 0);
        __syncthreads();
    }

#pragma unroll
    for (int ni = 0; ni < 4; ni++) {
        int gc = n0 + wn + ni * 16 + l15;
        float bias = B[gc];
#pragma unroll
        for (int mi = 0; mi < 4; mi++) {
#pragma unroll
            for (int r = 0; r < 4; r++) {
                int gr = t0 + wm + mi * 16 + quad * 4 + r;
                xp[((size_t)d * 4096 + gr) * 4096 + gc] = acc[mi][ni][r] + bias;
            }
        }
    }
}

// ---------------------------------------------------------------------------
// Kernel B: persistent bidirectional LSTM recurrence, fence-free tagged sync.
//
// Sync scheme (best measured, r4 = 8595 us): hq is uint32[dir][2][1024];
// each word = fp32 h with its 2 LOW MANTISSA BITS replaced by (step & 3).
// Parity double-buffer: a polled slot only ever holds step t or t-2 ->
// 2-bit tag fully disambiguates; perturbation <=3 ulp. memset-0 init ==
// tag 0 == h^0. Poll: ONE 8B relaxed agent-scope atomic load covers 2
// adjacent units; merged check + s_sleep(1) backoff (r3-proven; r7's
// deeper spin pipeline and r8's wave-autonomous full-vector poll both
// regressed -- poll mechanics are at their local optimum). Publish: 4B
// atomic store, issued before the out stores.
//
// Structure: 128 blocks x 512 threads, 16 units/block. NO pre-FMA barrier:
// wave w's hsh segment [128w,+128) is written and read only by itself
// (s_waitcnt lgkmcnt(0) orders it); each wave enters FMA on its OWN
// detect; coupling deferred to S2 where FMA time absorbs straggler spread.
// (r5's pre-FMA full barrier: -60%. r8's barrier-free wave-autonomous
// variant: -150% from 8x poll congestion.)
//
// Round-9 change: packed-fp32 GEMV inner loop. The 128-FMA chain is
// ~512 cy of serial VALU issue (2 waves/SIMD); expressing it as
// <2 x float> llvm.fma lets ISel select v_pk_fma_f32 (VOP3P, 2 FMA/inst,
// full fp32 precision -> absmax unchanged). Weights held as float2v
// register vectors (VGPR pairs, avoiding the AGPR-array allocation seen
// at VGPR_Count=112). __launch_bounds__(512,1): block shape still forces
// <=256 VGPR; actual residency is 1 block/CU (grid 128 < 256 CUs).
//
// Safety: a block publishes t+1 only after S2(t), which its tag-t polls
// precede; publish of t+2 (overwriting step-t slots) transitively requires
// every block's step-t polls completed. No clobber of live words.
// ---------------------------------------------------------------------------
template <int FUSED>
__global__ __launch_bounds__(512, 1)
void lstm_rec(const float* __restrict__ fw,
              const float* __restrict__ bw,
              const float* __restrict__ fb,
              const float* __restrict__ bb,
              const float* __restrict__ inp,
              const float* __restrict__ xp,
              unsigned int* __restrict__ hq,     // [dir][2][1024] tagged f32
              float* __restrict__ out)
{
    const int dir  = blockIdx.x & 1;
    const int slot = blockIdx.x >> 1;          // 0..63
    const int u0   = slot * 16;                // 16 units per block
    const int T    = threadIdx.x;              // 0..511
    const int rl   = T & 63;                   // z-row-local 0..63
    const int gate = rl >> 4;
    const int ul   = rl & 15;
    const int chunk = T >> 6;                  // wave id 0..7 (128-col chunk)
    const int j    = gate * 1024 + u0 + ul;    // global z-row
    const float* W = dir ? bw : fw;

    __shared__ __align__(16) float hsh[1024];
    __shared__ __align__(16) float xsh[1024];     // FUSED only
    __shared__ float psum[2][64 * 9];             // per-parity partials

    // Wh weights (cols [chunk*128,+128) of row j) -> float2v register pairs
    float2v wA[32], wB[32];
    {
        const float* wr = W + (size_t)j * 2048 + chunk * 128;
#pragma unroll
        for (int i = 0; i < 32; i++) {
            float4v v = *(const float4v*)&wr[4 * i];
            wA[i] = (float2v){v.x, v.y};
            wB[i] = (float2v){v.z, v.w};
        }
    }

    // FUSED: Wx packed bf16 + per-row bias
    unsigned int w2[64];
    float brow = 0.f;
    if (FUSED) {
        const float* wr2 = W + (size_t)j * 2048 + 1024 + chunk * 128;
#pragma unroll
        for (int i = 0; i < 32; i++) {
            float4v v = *(const float4v*)&wr2[4 * i];
            w2[2 * i]     = (unsigned int)f2bf(v[0]) | ((unsigned int)f2bf(v[1]) << 16);
            w2[2 * i + 1] = (unsigned int)f2bf(v[2]) | ((unsigned int)f2bf(v[3]) << 16);
        }
        if (T < 64)
            brow = (dir ? bb : fb)[(T >> 4) * 1024 + u0 + (T & 15)];
    }

    unsigned int* hqd = hq + dir * 2048;
    float c = 0.f;   // cell state for unit u0+T (threads T<16)

    for (int t = 0; t < 4096; t++) {
        const int tr  = dir ? (4095 - t) : t;
        const int par = t & 1;

        // independent global loads first (long latency, off critical path)
        float xv = 0.f;
        float2 iv;
        if (FUSED) {
            iv = ((const float2*)&inp[(size_t)tr * 1024])[T];
        } else if (T < 64) {
            xv = xp[((size_t)dir * 4096 + tr) * 4096 + j];
        }

        // poll pair T (units 2T,2T+1) with ONE 8B load; 2-bit embedded tags
        {
            const ull tag2 = ((ull)((unsigned)t & 3u)) * 0x100000001ull;
            ull* q0 = (ull*)(hqd + par * 1024 + 2 * T);
            ull w0 = __hip_atomic_load(q0, __ATOMIC_RELAXED, __HIP_MEMORY_SCOPE_AGENT);
            while ((w0 & 0x0000000300000003ull) != tag2) {
                __builtin_amdgcn_s_sleep(1);   // ~64 cy backoff, decongest fabric
                w0 = __hip_atomic_load(q0, __ATOMIC_RELAXED, __HIP_MEMORY_SCOPE_AGENT);
            }
            *(ull*)&hsh[2 * T] = w0;   // raw bits; tag bits are <=3 ulp noise
        }
        if (FUSED) {
            xsh[2 * T]     = iv.x;
            xsh[2 * T + 1] = iv.y;
        }
        // NO block barrier: hsh/xsh segment [chunk*128,+128) is private to
        // this wave. Order the same-wave LDS write->read explicitly.
        asm volatile("s_waitcnt lgkmcnt(0)" ::: "memory");

        // z partial: 64 packed-fp32 FMAs (v_pk_fma_f32; wave-broadcast LDS)
        float2v ac01 = {0.f, 0.f}, ac23 = {0.f, 0.f};
        const float4v* h4 = (const float4v*)&hsh[chunk * 128];
#pragma unroll
        for (int i = 0; i < 32; i++) {
            float4v hv = h4[i];
            float2v h01 = {hv.x, hv.y};
            float2v h23 = {hv.z, hv.w};
            ac01 = __builtin_elementwise_fma(wA[i], h01, ac01);
            ac23 = __builtin_elementwise_fma(wB[i], h23, ac23);
        }
        if (FUSED) {
            const float* xs = &xsh[chunk * 128];
#pragma unroll
            for (int i = 0; i < 64; i++) {
                unsigned int dv = w2[i];
                float2v xp2 = {xs[2 * i], xs[2 * i + 1]};
                float2v wd = {bf2f((unsigned short)(dv & 0xffffu)),
                              bf2f((unsigned short)(dv >> 16))};
                ac01 = __builtin_elementwise_fma(wd, xp2, ac01);
            }
        }
        psum[par][rl * 9 + chunk] = (ac01[0] + ac01[1]) + (ac23[0] + ac23[1]);
        __syncthreads();   // S2: psum ready

        // epilogue on wave 0: 64 row-reducers -> shfl gather -> 16 gate lanes.
        // Publish FIRST (critical path), then the out stores.
        if (T < 64) {
            float s = FUSED ? brow : xv;
            const float* pp = &psum[par][T * 9];
#pragma unroll
            for (int cc = 0; cc < 8; cc++) s += pp[cc];
            const int u = T & 15;
            float z0 = __shfl(s, u);           // gate f: row u
            float z1 = __shfl(s, u + 16);      // gate i
            float z2 = __shfl(s, u + 32);      // gate g
            float z3 = __shfl(s, u + 48);      // gate o
            if (T < 16) {
                c = sigm(z0) * c + sigm(z1) * tanh_fast(z2);
                float hv = sigm(z3) * tanh_fast(c);
                unsigned int hb = (__float_as_uint(hv) & ~3u)
                                | ((unsigned)(t + 1) & 3u);
                __hip_atomic_store(&hqd[((t + 1) & 1) * 1024 + u0 + T], hb,
                                   __ATOMIC_RELAXED, __HIP_MEMORY_SCOPE_AGENT);
                out[(size_t)tr * 2048 + dir * 1024 + u0 + T] = hv;
                if (t == 4095)   // final_h: fwd = hs[4095], bwd = hs[0]
                    out[(size_t)4096 * 2048 + dir * 1024 + u0 + T] = hv;
            }
        }
    }
}

// ---------------------------------------------------------------------------
extern "C" void kernel_launch(void* const* d_in, const int* in_sizes, int n_in,
                              void* d_out, int out_size, void* d_ws, size_t ws_size,
                              hipStream_t stream)
{
    const float* inp = (const float*)d_in[0];
    const float* fw  = (const float*)d_in[1];
    const float* fb  = (const float*)d_in[2];
    const float* bw  = (const float*)d_in[3];
    const float* bb  = (const float*)d_in[4];

    char* ws = (char*)d_ws;
    unsigned int* hq = (unsigned int*)ws;          // 16 KB: [dir][2][1024] x 4B
    float* xp = (float*)(ws + 32768);              // x_proj: 2 x 4096 x 4096 fp32

    const size_t XP_BYTES = 2ull * 4096 * 4096 * 4;   // 134.2 MB
    const int have_xp = (ws_size >= 32768 + XP_BYTES);

    hipMemsetAsync(ws, 0, 16384, stream);   // tag 0 / h=0 == step-0 state

    float* outp = (float*)d_out;
    if (have_xp) {
        dim3 gg(32, 32, 2);
        xproj_gemm<<<gg, 256, 0, stream>>>(inp, fw, fb, bw, bb, xp);
        lstm_rec<0><<<dim3(128), 512, 0, stream>>>(fw, bw, fb, bb, inp, xp,
                                                   hq, outp);
    } else {
        lstm_rec<1><<<dim3(128), 512, 0, stream>>>(fw, bw, fb, bb, inp, nullptr,
                                                   hq, outp);
    }
}